// Round 14
// baseline (557.151 us; speedup 1.0000x reference)
//
#include <hip/hip_runtime.h>
#include <math.h>

#define D 128
#define EPSV 1e-6f
#define CLIP_HI 1e6f
#define G 512            // colsum partial blocks
#define SLOTS 40         // ELL slots per row
#define HCF 128          // chunks per combo for direct fill (grid = 16*HCF)
#define EPB 2048         // edges per block in partition_edges
#define RANGES 64        // dst-ranges per direction (128 combos total)
#define NCOMBO (2 * RANGES)
#define FBC2 8           // blocks per combo in fill_from_queues
#define NCHUNK 4         // D-chunks (32 cols each) for L2-resident gathers
#define CMAX 56000       // max N for chunked path (N*64B <= ~3.58MB < 4MB L2)

typedef float v4f __attribute__((ext_vector_type(4)));
typedef float v2f __attribute__((ext_vector_type(2)));
typedef unsigned v4u __attribute__((ext_vector_type(4)));

// ---------------- bf16 helpers ----------------------------------------------
__device__ __forceinline__ unsigned short f2bf(float f) {
    unsigned u = __float_as_uint(f);
    u = u + 0x7FFFu + ((u >> 16) & 1u);   // round-to-nearest-even
    return (unsigned short)(u >> 16);
}
__device__ __forceinline__ void fma8v(uint4 u, float a, v2f* acc) {
    v2f a2 = {a, a};
    v2f p0 = {__uint_as_float(u.x << 16), __uint_as_float(u.x & 0xffff0000u)};
    v2f p1 = {__uint_as_float(u.y << 16), __uint_as_float(u.y & 0xffff0000u)};
    v2f p2 = {__uint_as_float(u.z << 16), __uint_as_float(u.z & 0xffff0000u)};
    v2f p3 = {__uint_as_float(u.w << 16), __uint_as_float(u.w & 0xffff0000u)};
    acc[0] += p0 * a2;
    acc[1] += p1 * a2;
    acc[2] += p2 * a2;
    acc[3] += p3 * a2;
}
__device__ __forceinline__ void unpack8(uint4 u, float* f) {
    f[0] = __uint_as_float(u.x << 16);
    f[1] = __uint_as_float(u.x & 0xffff0000u);
    f[2] = __uint_as_float(u.y << 16);
    f[3] = __uint_as_float(u.y & 0xffff0000u);
    f[4] = __uint_as_float(u.z << 16);
    f[5] = __uint_as_float(u.z & 0xffff0000u);
    f[6] = __uint_as_float(u.w << 16);
    f[7] = __uint_as_float(u.w & 0xffff0000u);
}
// ---------------- non-temporal access helpers -------------------------------
__device__ __forceinline__ float4 nt_load4f(const float* p) {
    v4f t = __builtin_nontemporal_load(reinterpret_cast<const v4f*>(p));
    return make_float4(t.x, t.y, t.z, t.w);
}
__device__ __forceinline__ void nt_store4f(float* p, float a, float b, float c, float d) {
    v4f t = {a, b, c, d};
    __builtin_nontemporal_store(t, reinterpret_cast<v4f*>(p));
}
__device__ __forceinline__ void nt_store4u(unsigned short* p, uint4 o) {
    v4u t = {o.x, o.y, o.z, o.w};
    __builtin_nontemporal_store(t, reinterpret_cast<v4u*>(p));
}
__device__ __forceinline__ long long nt_load_ll(const void* p) {
    return __builtin_nontemporal_load(reinterpret_cast<const long long*>(p));
}

// -------- alpha partial colsums + x->bf16 (optionally chunked layout) -------
__global__ __launch_bounds__(256) void colsum_bf16(
        const float* __restrict__ xA, const float* __restrict__ xB,
        int NA, int NB, float* __restrict__ partA, float* __restrict__ partB,
        unsigned short* __restrict__ tblA, unsigned short* __restrict__ tblB,
        int chunked) {
    __shared__ float4 sh[256];
    int tid = threadIdx.x;
    int c4  = tid & 31;   // float4 column chunk (cols c4*4..c4*4+3)
    int rs  = tid >> 5;   // 0..7 row sub-slot
    int cb  = c4 >> 3;    // D-chunk 0..3
    int cc  = c4 & 7;     // within-chunk ushort4 slot
    float4 sa = make_float4(0.f, 0.f, 0.f, 0.f);
    float4 sb = make_float4(0.f, 0.f, 0.f, 0.f);
    for (int r = blockIdx.x * 8 + rs; r < NA; r += gridDim.x * 8) {
        float4 v = nt_load4f(xA + (size_t)r * D + c4 * 4);
        sa.x += v.x; sa.y += v.y; sa.z += v.z; sa.w += v.w;
        ushort4 o; o.x = f2bf(v.x); o.y = f2bf(v.y); o.z = f2bf(v.z); o.w = f2bf(v.w);
        size_t adr = chunked ? ((size_t)cb * NA * 32 + (size_t)r * 32 + cc * 4)
                             : ((size_t)r * D + c4 * 4);
        *reinterpret_cast<ushort4*>(tblA + adr) = o;
    }
    for (int r = blockIdx.x * 8 + rs; r < NB; r += gridDim.x * 8) {
        float4 v = nt_load4f(xB + (size_t)r * D + c4 * 4);
        sb.x += v.x; sb.y += v.y; sb.z += v.z; sb.w += v.w;
        ushort4 o; o.x = f2bf(v.x); o.y = f2bf(v.y); o.z = f2bf(v.z); o.w = f2bf(v.w);
        size_t adr = chunked ? ((size_t)cb * NB * 32 + (size_t)r * 32 + cc * 4)
                             : ((size_t)r * D + c4 * 4);
        *reinterpret_cast<ushort4*>(tblB + adr) = o;
    }
    sh[tid] = sa; __syncthreads();
    if (tid < 128) { sh[tid].x += sh[tid+128].x; sh[tid].y += sh[tid+128].y; sh[tid].z += sh[tid+128].z; sh[tid].w += sh[tid+128].w; } __syncthreads();
    if (tid < 64)  { sh[tid].x += sh[tid+64].x;  sh[tid].y += sh[tid+64].y;  sh[tid].z += sh[tid+64].z;  sh[tid].w += sh[tid+64].w;  } __syncthreads();
    if (tid < 32)  {
        float4 t = sh[tid]; float4 u = sh[tid+32];
        t.x += u.x; t.y += u.y; t.z += u.z; t.w += u.w;
        *reinterpret_cast<float4*>(partA + (size_t)blockIdx.x * D + tid * 4) = t;
    }
    __syncthreads();
    sh[tid] = sb; __syncthreads();
    if (tid < 128) { sh[tid].x += sh[tid+128].x; sh[tid].y += sh[tid+128].y; sh[tid].z += sh[tid+128].z; sh[tid].w += sh[tid+128].w; } __syncthreads();
    if (tid < 64)  { sh[tid].x += sh[tid+64].x;  sh[tid].y += sh[tid+64].y;  sh[tid].z += sh[tid+64].z;  sh[tid].w += sh[tid+64].w;  } __syncthreads();
    if (tid < 32)  {
        float4 t = sh[tid]; float4 u = sh[tid+32];
        t.x += u.x; t.y += u.y; t.z += u.z; t.w += u.w;
        *reinterpret_cast<float4*>(partB + (size_t)blockIdx.x * D + tid * 4) = t;
    }
}

// ---------------- alpha: reduce partials + tiny MLP (wide) -------------------
__global__ __launch_bounds__(1024) void compute_alpha(
        const float* __restrict__ partA, const float* __restrict__ partB,
        int NA, int NB,
        const float* __restrict__ fc1_w, const float* __restrict__ fc1_b,
        const float* __restrict__ fc2_w, const float* __restrict__ fc2_b,
        float* __restrict__ alpha_out) {
    __shared__ float redA[1024];
    __shared__ float redB[1024];
    __shared__ float g[D];
    __shared__ float h[D];
    int tid = threadIdx.x;
    int c = tid & 127;
    int slice = tid >> 7;
    float sa = 0.f, sb = 0.f;
    for (int b = slice; b < G; b += 8) {
        sa += partA[(size_t)b * D + c];
        sb += partB[(size_t)b * D + c];
    }
    redA[tid] = sa; redB[tid] = sb;
    __syncthreads();
    if (tid < 512) { redA[tid] += redA[tid + 512]; redB[tid] += redB[tid + 512]; } __syncthreads();
    if (tid < 256) { redA[tid] += redA[tid + 256]; redB[tid] += redB[tid + 256]; } __syncthreads();
    if (tid < 128) {
        float ta = redA[tid] + redA[tid + 128];
        float tb = redB[tid] + redB[tid + 128];
        g[c] = 0.5f * (ta / (float)NA + tb / (float)NB);
    }
    __syncthreads();
    if (tid < 128) {
        float acc = fc1_b[c];
        for (int k = 0; k < D; ++k) acc += g[k] * fc1_w[(size_t)c * D + k];
        h[c] = tanhf(acc);
    }
    __syncthreads();
    if (tid == 0) {
        float a = fc2_b[0];
        for (int k = 0; k < D; ++k) a += h[k] * fc2_w[k];
        a = 1.f / (1.f + expf(-a));
        a = fminf(fmaxf(a, EPSV), 1.f - EPSV);
        *alpha_out = a;
    }
}

// --------- phase A: partition edges into 128 (dir,range) queues -------------
__global__ __launch_bounds__(256) void partition_edges(
        const int* __restrict__ eA, const float* __restrict__ attA, int NA,
        const int* __restrict__ eB, const float* __restrict__ attB, int NB,
        int E, int2* __restrict__ queues, int* __restrict__ qcnt, int qcap) {
    __shared__ int lcnt[NCOMBO];
    __shared__ int lbase[NCOMBO];
    int tid = threadIdx.x;
    int nbl = gridDim.x >> 1;
    int dir = (int)(blockIdx.x >= (unsigned)nbl);
    int blk = dir ? (blockIdx.x - nbl) : blockIdx.x;
    const int* e = dir ? eB : eA;
    const float* att = dir ? attB : attA;
    unsigned divN = (unsigned)(((dir ? NB : NA) + RANGES - 1) / RANGES);
    if (divN == 0) divN = 1;
    int start = blk * EPB;

    if (tid < NCOMBO) lcnt[tid] = 0;
    __syncthreads();

    int dstv[8], srcv[8], lp[8];
    float attv[8];
    int cb[8];
    #pragma unroll
    for (int k = 0; k < 8; ++k) {
        int i = start + k * 256 + tid;
        if (i < E) {
            int dst = __builtin_nontemporal_load(&e[E + i]);
            dstv[k] = dst;
            srcv[k] = __builtin_nontemporal_load(&e[i]);
            attv[k] = __builtin_nontemporal_load(&att[i]);
            unsigned range = (unsigned)dst / divN;
            if (range > RANGES - 1) range = RANGES - 1;
            cb[k] = dir * RANGES + (int)range;
            lp[k] = atomicAdd(&lcnt[cb[k]], 1);
        } else {
            cb[k] = -1; lp[k] = 0; dstv[k] = 0; srcv[k] = 0; attv[k] = 0.f;
        }
    }
    __syncthreads();
    if (tid < NCOMBO) lbase[tid] = atomicAdd(&qcnt[tid], lcnt[tid]);
    __syncthreads();
    #pragma unroll
    for (int k = 0; k < 8; ++k) {
        if (cb[k] >= 0) {
            int pos = lbase[cb[k]] + lp[k];
            if (pos < qcap) {
                int2 v;
                v.x = (dstv[k] << 16) | (srcv[k] & 0xffff);
                v.y = __float_as_int(attv[k]);
                queues[(size_t)cb[k] * qcap + pos] = v;
            }
        }
    }
}

// --------- phase B: fill ELL from queues (fine combos, XCD-pinned) ----------
__global__ __launch_bounds__(256) void fill_from_queues(
        const int2* __restrict__ queues, const int* __restrict__ qcnt, int qcap,
        int* __restrict__ cntA, int2* __restrict__ ellA,
        int* __restrict__ cntB, int2* __restrict__ ellB) {
    int combo = blockIdx.x & (NCOMBO - 1);
    int chunk = blockIdx.x >> 7;
    int dir = combo >> 6;
    int* cnt  = dir ? cntB : cntA;
    int2* ell = dir ? ellB : ellA;
    int n = qcnt[combo];
    if (n > qcap) n = qcap;
    const int2* q = queues + (size_t)combo * qcap;
    for (int i = chunk * 256 + threadIdx.x; i < n; i += FBC2 * 256) {
        long long raw = nt_load_ll(&q[i]);
        int key = (int)(unsigned)raw;
        int dst = ((unsigned)key) >> 16;
        int src = key & 0xffff;
        int pos = atomicAdd(&cnt[dst], 1);
        if (pos < SLOTS) {
            int2 w; w.x = src; w.y = (int)(raw >> 32);
            ell[(size_t)dst * SLOTS + pos] = w;
        }
    }
}

// ------------- direct fill (for big-N / non-chunked tier) -------------------
__global__ __launch_bounds__(256) void fill_direct(
        const int* __restrict__ eA, const float* __restrict__ attA,
        int* __restrict__ cntA, int2* __restrict__ ellA, int NA,
        const int* __restrict__ eB, const float* __restrict__ attB,
        int* __restrict__ cntB, int2* __restrict__ ellB, int NB, int E) {
    int b = blockIdx.x;
    int combo = b & 15;
    int dir   = combo >> 3;
    int range = combo & 7;
    int chunk = b >> 4;
    const int* e; const float* att; int* cnt; int2* ell; int N;
    if (dir == 0) { e = eA; att = attA; cnt = cntA; ell = ellA; N = NA; }
    else          { e = eB; att = attB; cnt = cntB; ell = ellB; N = NB; }
    int lo = (int)((long)range * N >> 3), hi = (int)((long)(range + 1) * N >> 3);
    for (int i = chunk * 256 + threadIdx.x; i < E; i += HCF * 256) {
        int dst = __builtin_nontemporal_load(&e[E + i]);
        if (dst >= lo && dst < hi) {
            int pos = atomicAdd(&cnt[dst], 1);
            if (pos < SLOTS) {
                int2 v;
                v.x = __builtin_nontemporal_load(&e[i]);
                v.y = __float_as_int(__builtin_nontemporal_load(&att[i]));
                ell[(size_t)dst * SLOTS + pos] = v;
            }
        }
    }
}

// ------- D-chunked ELL aggregate: gather working set fits per-XCD L2 --------
// One pass handles 32 columns (chunk ck). Wave = 1 row; 16 slot-groups x
// 4 lanes x 8 bf16 = 16 edges/round, masked. Gather table chunk (~3.2MB/dir)
// is L2-resident. ELL reads nt (stream); table gathers NORMAL.
// Pointers gt/fx/obf are PRE-OFFSET to chunk ck by host. of32 full-width + ck.
template <int LAST>
__global__ __launch_bounds__(256) void aggregate7(
        const int* __restrict__ cntA, const int2* __restrict__ ellA,
        const unsigned short* __restrict__ gtA, const unsigned short* __restrict__ fxA,
        unsigned short* __restrict__ obfA, float* __restrict__ of32A, int NA,
        const int* __restrict__ cntB, const int2* __restrict__ ellB,
        const unsigned short* __restrict__ gtB, const unsigned short* __restrict__ fxB,
        unsigned short* __restrict__ obfB, float* __restrict__ of32B, int NB,
        const float* __restrict__ alpha_p, int ck) {
    int grp = blockIdx.x >> 3;
    int sub = blockIdx.x & 7;            // XCD id under round-robin
    int rb  = grp * 4 + (sub & 3);       // per-direction row-block index
    int wid = threadIdx.x >> 6;          // wave in block: 0..3
    int lane = threadIdx.x & 63;
    int g = lane >> 2;                   // slot group 0..15
    int l = lane & 3;                    // 4 lanes per edge, 8 cols each
    const int* cnt; const int2* ellbase; const unsigned short* gt; const unsigned short* fx;
    unsigned short* obf; float* of32; int N;
    if (sub < 4) {
        cnt = cntA; ellbase = ellA; gt = gtA; fx = fxA;
        obf = obfA; of32 = of32A; N = NA;
    } else {
        cnt = cntB; ellbase = ellB; gt = gtB; fx = fxB;
        obf = obfB; of32 = of32B; N = NB;
    }
    int row = rb * 4 + wid;
    if (row >= N) return;                // uniform per wave
    int c = cnt[row];
    int deg = c < SLOTS ? c : SLOTS;
    const int2* ent = ellbase + (size_t)row * SLOTS;
    v2f acc2[4];
    acc2[0] = (v2f){0.f, 0.f}; acc2[1] = (v2f){0.f, 0.f};
    acc2[2] = (v2f){0.f, 0.f}; acc2[3] = (v2f){0.f, 0.f};
    int off = l * 8;

#define PROC16C(BASE)                                                         \
    {                                                                         \
        int slot = (BASE) + g;                                                \
        long long rr = nt_load_ll(&ent[slot]);                                \
        bool valid = slot < deg;                                              \
        unsigned sv = valid ? (unsigned)rr : 0u;                              \
        float av = valid ? __int_as_float((int)(rr >> 32)) : 0.0f;            \
        uint4 u = *reinterpret_cast<const uint4*>(gt + (size_t)sv * 32 + off);\
        fma8v(u, av, acc2);                                                   \
    }

    PROC16C(0);                              // covers deg <= 16 (~84% of rows)
    for (int base = 16; base < deg; base += 16) PROC16C(base);
#undef PROC16C

    // reduce across the 16 slot-groups (lanes with same l)
    float acc[8];
    #pragma unroll
    for (int k = 0; k < 4; ++k) { acc[2*k] = acc2[k][0]; acc[2*k+1] = acc2[k][1]; }
    #pragma unroll
    for (int k = 0; k < 8; ++k) {
        acc[k] += __shfl_xor(acc[k], 4);
        acc[k] += __shfl_xor(acc[k], 8);
        acc[k] += __shfl_xor(acc[k], 16);
        acc[k] += __shfl_xor(acc[k], 32);
    }
    if (g == 0) {
        float al = alpha_p[0], bl = 1.f - al;
        float fv[8];
        uint4 f = *reinterpret_cast<const uint4*>(fx + (size_t)row * 32 + off);
        unpack8(f, fv);
        float r[8];
        #pragma unroll
        for (int k = 0; k < 8; ++k)
            r[k] = fminf(fmaxf(fv[k] * al + acc[k] * bl, EPSV), CLIP_HI);
        if (LAST) {
            float* po = of32 + (size_t)row * D + ck * 32 + off;
            nt_store4f(po,     r[0], r[1], r[2], r[3]);
            nt_store4f(po + 4, r[4], r[5], r[6], r[7]);
        } else {
            uint4 o;
            o.x = (unsigned)f2bf(r[0]) | ((unsigned)f2bf(r[1]) << 16);
            o.y = (unsigned)f2bf(r[2]) | ((unsigned)f2bf(r[3]) << 16);
            o.z = (unsigned)f2bf(r[4]) | ((unsigned)f2bf(r[5]) << 16);
            o.w = (unsigned)f2bf(r[6]) | ((unsigned)f2bf(r[7]) << 16);
            nt_store4u(obf + (size_t)row * 32 + off, o);
        }
    }
}

// ------- full-D ELL aggregate (big-N tier, r13 form) -------------------------
template <int LAST>
__global__ __launch_bounds__(256) void aggregate6(
        const int* __restrict__ cntA, const int2* __restrict__ ellA,
        const unsigned short* __restrict__ gtA, const unsigned short* __restrict__ fxA,
        unsigned short* __restrict__ obfA, float* __restrict__ of32A, int NA,
        const int* __restrict__ cntB, const int2* __restrict__ ellB,
        const unsigned short* __restrict__ gtB, const unsigned short* __restrict__ fxB,
        unsigned short* __restrict__ obfB, float* __restrict__ of32B, int NB,
        const float* __restrict__ alpha_p) {
    int grp = blockIdx.x >> 3;
    int sub = blockIdx.x & 7;
    int rb  = grp * 4 + (sub & 3);
    int wid = threadIdx.x >> 6;
    int lane = threadIdx.x & 63;
    int g = lane >> 4;
    int l = lane & 15;
    const int* cnt; const int2* ellbase; const unsigned short* gt; const unsigned short* fx;
    unsigned short* obf; float* of32; int N;
    if (sub < 4) {
        cnt = cntA; ellbase = ellA; gt = gtA; fx = fxA;
        obf = obfA; of32 = of32A; N = NA;
    } else {
        cnt = cntB; ellbase = ellB; gt = gtB; fx = fxB;
        obf = obfB; of32 = of32B; N = NB;
    }
    int row = rb * 4 + wid;
    if (row >= N) return;
    int c = cnt[row];
    int deg = c < SLOTS ? c : SLOTS;
    const int2* ent = ellbase + (size_t)row * SLOTS;
    v2f acc2[4];
    acc2[0] = (v2f){0.f, 0.f}; acc2[1] = (v2f){0.f, 0.f};
    acc2[2] = (v2f){0.f, 0.f}; acc2[3] = (v2f){0.f, 0.f};
    int off = l * 8;

#define PROC16(BASE)                                                          \
    {                                                                         \
        unsigned sv[4]; float av[4]; uint4 u[4];                              \
        _Pragma("unroll")                                                     \
        for (int k = 0; k < 4; ++k) {                                         \
            int slot = (BASE) + k * 4 + g;                                    \
            long long rr = nt_load_ll(&ent[slot]);                            \
            bool valid = slot < deg;                                          \
            sv[k] = valid ? (unsigned)rr : 0u;                                \
            av[k] = valid ? __int_as_float((int)(rr >> 32)) : 0.0f;           \
        }                                                                     \
        _Pragma("unroll")                                                     \
        for (int k = 0; k < 4; ++k)                                           \
            u[k] = *reinterpret_cast<const uint4*>(gt + (size_t)sv[k] * D + off); \
        _Pragma("unroll")                                                     \
        for (int k = 0; k < 4; ++k) fma8v(u[k], av[k], acc2);                 \
    }

    PROC16(0);
    for (int base = 16; base < deg; base += 16) PROC16(base);
#undef PROC16

    float acc[8];
    #pragma unroll
    for (int k = 0; k < 4; ++k) { acc[2*k] = acc2[k][0]; acc[2*k+1] = acc2[k][1]; }
    #pragma unroll
    for (int k = 0; k < 8; ++k) {
        acc[k] += __shfl_xor(acc[k], 16);
        acc[k] += __shfl_xor(acc[k], 32);
    }
    if (g == 0) {
        float al = alpha_p[0], bl = 1.f - al;
        float fv[8];
        uint4 f = *reinterpret_cast<const uint4*>(fx + (size_t)row * D + off);
        unpack8(f, fv);
        float r[8];
        #pragma unroll
        for (int k = 0; k < 8; ++k)
            r[k] = fminf(fmaxf(fv[k] * al + acc[k] * bl, EPSV), CLIP_HI);
        if (LAST) {
            nt_store4f(of32 + (size_t)row * D + off,     r[0], r[1], r[2], r[3]);
            nt_store4f(of32 + (size_t)row * D + off + 4, r[4], r[5], r[6], r[7]);
        } else {
            uint4 o;
            o.x = (unsigned)f2bf(r[0]) | ((unsigned)f2bf(r[1]) << 16);
            o.y = (unsigned)f2bf(r[2]) | ((unsigned)f2bf(r[3]) << 16);
            o.z = (unsigned)f2bf(r[4]) | ((unsigned)f2bf(r[5]) << 16);
            o.w = (unsigned)f2bf(r[6]) | ((unsigned)f2bf(r[7]) << 16);
            nt_store4u(obf + (size_t)row * D + off, o);
        }
    }
}

// ---------------- fallback (atomic scatter) kernels --------------------------
__global__ void scatter_add(const float* __restrict__ cur, const float* __restrict__ att,
                            const int* __restrict__ edges, int E,
                            float* __restrict__ msg) {
    const long long total = (long long)E * (D / 4);
    long long stride = (long long)gridDim.x * blockDim.x;
    for (long long idx = (long long)blockIdx.x * blockDim.x + threadIdx.x;
         idx < total; idx += stride) {
        int e  = (int)(idx >> 5);
        int ch = (int)(idx & 31);
        int src = edges[e];
        int dst = edges[E + e];
        float a = att[e];
        const float4 v = *reinterpret_cast<const float4*>(cur + (size_t)src * D + ch * 4);
        float* p = msg + (size_t)dst * D + ch * 4;
        atomicAdd(p + 0, v.x * a);
        atomicAdd(p + 1, v.y * a);
        atomicAdd(p + 2, v.z * a);
        atomicAdd(p + 3, v.w * a);
    }
}

__global__ void combine(const float4* __restrict__ feat0, const float4* __restrict__ msg,
                        const float* __restrict__ alpha_p, float4* __restrict__ out, int n4) {
    float a = alpha_p[0];
    float b = 1.f - a;
    int stride = gridDim.x * blockDim.x;
    for (int i = blockIdx.x * blockDim.x + threadIdx.x; i < n4; i += stride) {
        float4 f = feat0[i];
        float4 m = msg[i];
        float4 r;
        r.x = fminf(fmaxf(f.x * a + m.x * b, EPSV), CLIP_HI);
        r.y = fminf(fmaxf(f.y * a + m.y * b, EPSV), CLIP_HI);
        r.z = fminf(fmaxf(f.z * a + m.z * b, EPSV), CLIP_HI);
        r.w = fminf(fmaxf(f.w * a + m.w * b, EPSV), CLIP_HI);
        out[i] = r;
    }
}

extern "C" void kernel_launch(void* const* d_in, const int* in_sizes, int n_in,
                              void* d_out, int out_size, void* d_ws, size_t ws_size,
                              hipStream_t stream) {
    const float* xA    = (const float*)d_in[0];
    const float* xB    = (const float*)d_in[1];
    const float* attAB = (const float*)d_in[2];
    const float* attBA = (const float*)d_in[3];
    const float* fc1_w = (const float*)d_in[4];
    const float* fc1_b = (const float*)d_in[5];
    const float* fc2_w = (const float*)d_in[6];
    const float* fc2_b = (const float*)d_in[7];
    const int*   eAB   = (const int*)d_in[8];   // src in A, dst in B
    const int*   eBA   = (const int*)d_in[9];   // src in B, dst in A

    const int NA = in_sizes[0] / D;
    const int NB = in_sizes[1] / D;
    const int E  = in_sizes[2];

    float* out  = (float*)d_out;
    float* outA = out;                      // [NA, D]
    float* outB = out + (size_t)NA * D;     // [NB, D]

    const size_t TBL = (size_t)(NA + NB) * D;   // elements (bf16)

    // ======== tier 0/1: ELL layout ========
    {
        unsigned short* tblP = (unsigned short*)d_ws;
        unsigned short* tblQ = tblP + TBL;
        unsigned short* xtab = tblQ + TBL;
        int2*  ellA  = (int2*)(xtab + TBL);
        int2*  ellB  = ellA + ((size_t)NA * SLOTS + 16);
        int*   cntA  = (int*)(ellB + ((size_t)NB * SLOTS + 16));
        int*   cntB  = cntA + NA;
        int*   qcnt  = cntB + NB;                          // NCOMBO ints
        float* partA = (float*)(qcnt + NCOMBO);
        float* partB = partA + (size_t)G * D;
        float* alpha = partB + (size_t)G * D;
        size_t needed = (size_t)((char*)(alpha + 4) - (char*)d_ws);

        if (ws_size >= needed) {
            unsigned short* xtabA = xtab, *xtabB = xtab + (size_t)NA * D;
            unsigned short* tblPA = tblP, *tblPB = tblP + (size_t)NA * D;
            unsigned short* tblQA = tblQ, *tblQB = tblQ + (size_t)NA * D;

            int qcap = E / RANGES + E / (4 * RANGES) + 2048;
            bool small_idx = (NA < 65536) && (NB < 65536);
            bool qfit = (size_t)NCOMBO * (size_t)qcap * sizeof(int2)
                        <= (size_t)out_size * sizeof(float);
            bool use_chunked = small_idx && qfit && (NA <= CMAX) && (NB <= CMAX);

            colsum_bf16<<<G, 256, 0, stream>>>(xA, xB, NA, NB, partA, partB,
                                               xtabA, xtabB, use_chunked ? 1 : 0);
            compute_alpha<<<1, 1024, 0, stream>>>(partA, partB, NA, NB,
                                                  fc1_w, fc1_b, fc2_w, fc2_b, alpha);

            hipMemsetAsync(cntA, 0, ((size_t)NA + NB + NCOMBO) * sizeof(int), stream);

            if (use_chunked) {
                int2* queues = (int2*)d_out;   // dead until hop 2
                int nbl = (E + EPB - 1) / EPB;
                partition_edges<<<2 * nbl, 256, 0, stream>>>(
                    eBA, attBA, NA, eAB, attAB, NB, E, queues, qcnt, qcap);
                fill_from_queues<<<NCOMBO * FBC2, 256, 0, stream>>>(
                    queues, qcnt, qcap, cntA, ellA, cntB, ellB);

                int gA = (NA + 3) / 4, gB = (NB + 3) / 4;
                int gmax = gA > gB ? gA : gB;
                int grid = ((gmax + 3) / 4) * 8;
                size_t ca = (size_t)NA * 32, cbk = (size_t)NB * 32;
                for (int ck = 0; ck < NCHUNK; ++ck) {
                    // hop 0: xtab -> tblP (chunk ck)
                    aggregate7<0><<<grid, 256, 0, stream>>>(
                        cntA, ellA, xtabB + ck * cbk, xtabA + ck * ca,
                        tblPA + ck * ca, nullptr, NA,
                        cntB, ellB, xtabA + ck * ca, xtabB + ck * cbk,
                        tblPB + ck * cbk, nullptr, NB, alpha, ck);
                }
                for (int ck = 0; ck < NCHUNK; ++ck) {
                    // hop 1: tblP -> tblQ
                    aggregate7<0><<<grid, 256, 0, stream>>>(
                        cntA, ellA, tblPB + ck * cbk, xtabA + ck * ca,
                        tblQA + ck * ca, nullptr, NA,
                        cntB, ellB, tblPA + ck * ca, xtabB + ck * cbk,
                        tblQB + ck * cbk, nullptr, NB, alpha, ck);
                }
                for (int ck = 0; ck < NCHUNK; ++ck) {
                    // hop 2: tblQ -> d_out (fp32 cols ck*32..)
                    aggregate7<1><<<grid, 256, 0, stream>>>(
                        cntA, ellA, tblQB + ck * cbk, xtabA + ck * ca,
                        nullptr, outA, NA,
                        cntB, ellB, tblQA + ck * ca, xtabB + ck * cbk,
                        nullptr, outB, NB, alpha, ck);
                }
            } else {
                fill_direct<<<16 * HCF, 256, 0, stream>>>(
                    eBA, attBA, cntA, ellA, NA, eAB, attAB, cntB, ellB, NB, E);
                int gA = (NA + 3) / 4, gB = (NB + 3) / 4;
                int gmax = gA > gB ? gA : gB;
                int grid = ((gmax + 3) / 4) * 8;
                aggregate6<0><<<grid, 256, 0, stream>>>(
                    cntA, ellA, xtabB, xtabA, tblPA, nullptr, NA,
                    cntB, ellB, xtabA, xtabB, tblPB, nullptr, NB, alpha);
                aggregate6<0><<<grid, 256, 0, stream>>>(
                    cntA, ellA, tblPB, xtabA, tblQA, nullptr, NA,
                    cntB, ellB, tblPA, xtabB, tblQB, nullptr, NB, alpha);
                aggregate6<1><<<grid, 256, 0, stream>>>(
                    cntA, ellA, tblQB, xtabA, nullptr, outA, NA,
                    cntB, ellB, tblQA, xtabB, nullptr, outB, NB, alpha);
            }
            return;
        }
    }

    // ======== fallback: atomic scatter ========
    {
        float* msgA  = (float*)d_ws;
        float* msgB  = msgA + (size_t)NA * D;
        float* pA    = msgB + (size_t)NB * D;
        float* pB    = pA + (size_t)G * D;
        float* alph  = pB + (size_t)G * D;

        colsum_bf16<<<G, 256, 0, stream>>>(xA, xB, NA, NB, pA, pB,
                                           (unsigned short*)msgA, (unsigned short*)msgB, 0);
        compute_alpha<<<1, 1024, 0, stream>>>(pA, pB, NA, NB,
                                              fc1_w, fc1_b, fc2_w, fc2_b, alph);

        const size_t msgBytes = ((size_t)NA + (size_t)NB) * D * sizeof(float);
        for (int hop = 0; hop < 3; ++hop) {
            hipMemsetAsync(msgA, 0, msgBytes, stream);
            const float* fA = (hop == 0) ? xA : outA;
            const float* fB = (hop == 0) ? xB : outB;
            scatter_add<<<4096, 256, 0, stream>>>(fB, attBA, eBA, E, msgA);
            scatter_add<<<4096, 256, 0, stream>>>(fA, attAB, eAB, E, msgB);
            combine<<<2048, 256, 0, stream>>>((const float4*)xA, (const float4*)msgA,
                                              alph, (float4*)outA, NA * D / 4);
            combine<<<2048, 256, 0, stream>>>((const float4*)xB, (const float4*)msgB,
                                              alph, (float4*)outB, NB * D / 4);
        }
    }
}

// Round 15
// 255.017 us; speedup vs baseline: 2.1848x; 2.1848x over previous
//
#include <hip/hip_runtime.h>
#include <math.h>

#define D 128
#define EPSV 1e-6f
#define CLIP_HI 1e6f
#define G 512            // colsum partial blocks
#define SLOTS 40         // ELL slots per row (P[Poisson(12.5)>=40]*100k ~ 3e-5)
#define HCF 128          // chunks per combo for direct fill (grid = 16*HCF)
#define EPB 2048         // edges per block in partition_edges
#define RANGES 64        // dst-ranges per direction (128 combos total)
#define NCOMBO (2 * RANGES)
#define FBC2 8           // blocks per combo in fill_from_queues

typedef float v4f __attribute__((ext_vector_type(4)));
typedef float v2f __attribute__((ext_vector_type(2)));
typedef unsigned v4u __attribute__((ext_vector_type(4)));

// ---------------- bf16 helpers ----------------------------------------------
__device__ __forceinline__ unsigned short f2bf(float f) {
    unsigned u = __float_as_uint(f);
    u = u + 0x7FFFu + ((u >> 16) & 1u);   // round-to-nearest-even
    return (unsigned short)(u >> 16);
}
// fma 8 bf16 elements (packed in uint4) * a into 4x v2f acc (v_pk_fma_f32)
__device__ __forceinline__ void fma8v(uint4 u, float a, v2f* acc) {
    v2f a2 = {a, a};
    v2f p0 = {__uint_as_float(u.x << 16), __uint_as_float(u.x & 0xffff0000u)};
    v2f p1 = {__uint_as_float(u.y << 16), __uint_as_float(u.y & 0xffff0000u)};
    v2f p2 = {__uint_as_float(u.z << 16), __uint_as_float(u.z & 0xffff0000u)};
    v2f p3 = {__uint_as_float(u.w << 16), __uint_as_float(u.w & 0xffff0000u)};
    acc[0] += p0 * a2;
    acc[1] += p1 * a2;
    acc[2] += p2 * a2;
    acc[3] += p3 * a2;
}
__device__ __forceinline__ void unpack8(uint4 u, float* f) {
    f[0] = __uint_as_float(u.x << 16);
    f[1] = __uint_as_float(u.x & 0xffff0000u);
    f[2] = __uint_as_float(u.y << 16);
    f[3] = __uint_as_float(u.y & 0xffff0000u);
    f[4] = __uint_as_float(u.z << 16);
    f[5] = __uint_as_float(u.z & 0xffff0000u);
    f[6] = __uint_as_float(u.w << 16);
    f[7] = __uint_as_float(u.w & 0xffff0000u);
}
// ---------------- non-temporal access helpers -------------------------------
__device__ __forceinline__ float4 nt_load4f(const float* p) {
    v4f t = __builtin_nontemporal_load(reinterpret_cast<const v4f*>(p));
    return make_float4(t.x, t.y, t.z, t.w);
}
__device__ __forceinline__ void nt_store4f(float* p, float a, float b, float c, float d) {
    v4f t = {a, b, c, d};
    __builtin_nontemporal_store(t, reinterpret_cast<v4f*>(p));
}
__device__ __forceinline__ void nt_store4u(unsigned short* p, uint4 o) {
    v4u t = {o.x, o.y, o.z, o.w};
    __builtin_nontemporal_store(t, reinterpret_cast<v4u*>(p));
}
__device__ __forceinline__ long long nt_load_ll(const void* p) {
    return __builtin_nontemporal_load(reinterpret_cast<const long long*>(p));
}

// -------- alpha partial colsums + x->bf16 conversion (fused, one x pass) ----
__global__ __launch_bounds__(256) void colsum_bf16(
        const float* __restrict__ xA, const float* __restrict__ xB,
        int NA, int NB, float* __restrict__ partA, float* __restrict__ partB,
        unsigned short* __restrict__ tblA, unsigned short* __restrict__ tblB) {
    __shared__ float4 sh[256];
    int tid = threadIdx.x;
    int c4  = tid & 31;   // float4 column chunk
    int rs  = tid >> 5;   // 0..7 row sub-slot
    float4 sa = make_float4(0.f, 0.f, 0.f, 0.f);
    float4 sb = make_float4(0.f, 0.f, 0.f, 0.f);
    for (int r = blockIdx.x * 8 + rs; r < NA; r += gridDim.x * 8) {
        float4 v = nt_load4f(xA + (size_t)r * D + c4 * 4);
        sa.x += v.x; sa.y += v.y; sa.z += v.z; sa.w += v.w;
        ushort4 o; o.x = f2bf(v.x); o.y = f2bf(v.y); o.z = f2bf(v.z); o.w = f2bf(v.w);
        *reinterpret_cast<ushort4*>(tblA + (size_t)r * D + c4 * 4) = o;
    }
    for (int r = blockIdx.x * 8 + rs; r < NB; r += gridDim.x * 8) {
        float4 v = nt_load4f(xB + (size_t)r * D + c4 * 4);
        sb.x += v.x; sb.y += v.y; sb.z += v.z; sb.w += v.w;
        ushort4 o; o.x = f2bf(v.x); o.y = f2bf(v.y); o.z = f2bf(v.z); o.w = f2bf(v.w);
        *reinterpret_cast<ushort4*>(tblB + (size_t)r * D + c4 * 4) = o;
    }
    sh[tid] = sa; __syncthreads();
    if (tid < 128) { sh[tid].x += sh[tid+128].x; sh[tid].y += sh[tid+128].y; sh[tid].z += sh[tid+128].z; sh[tid].w += sh[tid+128].w; } __syncthreads();
    if (tid < 64)  { sh[tid].x += sh[tid+64].x;  sh[tid].y += sh[tid+64].y;  sh[tid].z += sh[tid+64].z;  sh[tid].w += sh[tid+64].w;  } __syncthreads();
    if (tid < 32)  {
        float4 t = sh[tid]; float4 u = sh[tid+32];
        t.x += u.x; t.y += u.y; t.z += u.z; t.w += u.w;
        *reinterpret_cast<float4*>(partA + (size_t)blockIdx.x * D + tid * 4) = t;
    }
    __syncthreads();
    sh[tid] = sb; __syncthreads();
    if (tid < 128) { sh[tid].x += sh[tid+128].x; sh[tid].y += sh[tid+128].y; sh[tid].z += sh[tid+128].z; sh[tid].w += sh[tid+128].w; } __syncthreads();
    if (tid < 64)  { sh[tid].x += sh[tid+64].x;  sh[tid].y += sh[tid+64].y;  sh[tid].z += sh[tid+64].z;  sh[tid].w += sh[tid+64].w;  } __syncthreads();
    if (tid < 32)  {
        float4 t = sh[tid]; float4 u = sh[tid+32];
        t.x += u.x; t.y += u.y; t.z += u.z; t.w += u.w;
        *reinterpret_cast<float4*>(partB + (size_t)blockIdx.x * D + tid * 4) = t;
    }
}

// ---------------- alpha: reduce partials + tiny MLP (wide) -------------------
__global__ __launch_bounds__(1024) void compute_alpha(
        const float* __restrict__ partA, const float* __restrict__ partB,
        int NA, int NB,
        const float* __restrict__ fc1_w, const float* __restrict__ fc1_b,
        const float* __restrict__ fc2_w, const float* __restrict__ fc2_b,
        float* __restrict__ alpha_out) {
    __shared__ float redA[1024];
    __shared__ float redB[1024];
    __shared__ float g[D];
    __shared__ float h[D];
    int tid = threadIdx.x;
    int c = tid & 127;        // column
    int slice = tid >> 7;     // 0..7
    float sa = 0.f, sb = 0.f;
    for (int b = slice; b < G; b += 8) {
        sa += partA[(size_t)b * D + c];
        sb += partB[(size_t)b * D + c];
    }
    redA[tid] = sa; redB[tid] = sb;
    __syncthreads();
    if (tid < 512) { redA[tid] += redA[tid + 512]; redB[tid] += redB[tid + 512]; } __syncthreads();
    if (tid < 256) { redA[tid] += redA[tid + 256]; redB[tid] += redB[tid + 256]; } __syncthreads();
    if (tid < 128) {
        float ta = redA[tid] + redA[tid + 128];
        float tb = redB[tid] + redB[tid + 128];
        g[c] = 0.5f * (ta / (float)NA + tb / (float)NB);
    }
    __syncthreads();
    if (tid < 128) {
        float acc = fc1_b[c];
        for (int k = 0; k < D; ++k) acc += g[k] * fc1_w[(size_t)c * D + k];
        h[c] = tanhf(acc);
    }
    __syncthreads();
    if (tid == 0) {
        float a = fc2_b[0];
        for (int k = 0; k < D; ++k) a += h[k] * fc2_w[k];
        a = 1.f / (1.f + expf(-a));
        a = fminf(fmaxf(a, EPSV), 1.f - EPSV);
        *alpha_out = a;
    }
}

// --------- phase A: partition edges into 128 (dir,range) queues -------------
// Each block handles EPB contiguous edges of one direction. LDS-aggregated
// per-combo counts -> 128 global atomics per block. Payload: (dst<<16|src, att).
__global__ __launch_bounds__(256) void partition_edges(
        const int* __restrict__ eA, const float* __restrict__ attA, int NA,
        const int* __restrict__ eB, const float* __restrict__ attB, int NB,
        int E, int2* __restrict__ queues, int* __restrict__ qcnt, int qcap) {
    __shared__ int lcnt[NCOMBO];
    __shared__ int lbase[NCOMBO];
    int tid = threadIdx.x;
    int nbl = gridDim.x >> 1;
    int dir = (int)(blockIdx.x >= (unsigned)nbl);
    int blk = dir ? (blockIdx.x - nbl) : blockIdx.x;
    const int* e = dir ? eB : eA;
    const float* att = dir ? attB : attA;
    unsigned divN = (unsigned)(((dir ? NB : NA) + RANGES - 1) / RANGES);
    if (divN == 0) divN = 1;
    int start = blk * EPB;

    if (tid < NCOMBO) lcnt[tid] = 0;
    __syncthreads();

    int dstv[8], srcv[8], lp[8];
    float attv[8];
    int cb[8];
    #pragma unroll
    for (int k = 0; k < 8; ++k) {
        int i = start + k * 256 + tid;
        if (i < E) {
            int dst = __builtin_nontemporal_load(&e[E + i]);
            dstv[k] = dst;
            srcv[k] = __builtin_nontemporal_load(&e[i]);
            attv[k] = __builtin_nontemporal_load(&att[i]);
            unsigned range = (unsigned)dst / divN;
            if (range > RANGES - 1) range = RANGES - 1;
            cb[k] = dir * RANGES + (int)range;
            lp[k] = atomicAdd(&lcnt[cb[k]], 1);
        } else {
            cb[k] = -1; lp[k] = 0; dstv[k] = 0; srcv[k] = 0; attv[k] = 0.f;
        }
    }
    __syncthreads();
    if (tid < NCOMBO) lbase[tid] = atomicAdd(&qcnt[tid], lcnt[tid]);
    __syncthreads();
    #pragma unroll
    for (int k = 0; k < 8; ++k) {
        if (cb[k] >= 0) {
            int pos = lbase[cb[k]] + lp[k];
            if (pos < qcap) {
                int2 v;
                v.x = (dstv[k] << 16) | (srcv[k] & 0xffff);
                v.y = __float_as_int(attv[k]);
                queues[(size_t)cb[k] * qcap + pos] = v;
            }
        }
    }
}

// --------- phase B: fill ELL from queues (fine combos, XCD-pinned) ----------
// combo = blockIdx&127 -> combo&7 == blockIdx&7 == XCD under round-robin.
// Each combo's ELL region ~250KB: all writes to a row's lines happen within
// one short queue scan -> lines accumulate fully in L2 before write-back.
__global__ __launch_bounds__(256) void fill_from_queues(
        const int2* __restrict__ queues, const int* __restrict__ qcnt, int qcap,
        int* __restrict__ cntA, int2* __restrict__ ellA,
        int* __restrict__ cntB, int2* __restrict__ ellB) {
    int combo = blockIdx.x & (NCOMBO - 1);
    int chunk = blockIdx.x >> 7;
    int dir = combo >> 6;                 // combo / RANGES
    int* cnt  = dir ? cntB : cntA;
    int2* ell = dir ? ellB : ellA;
    int n = qcnt[combo];
    if (n > qcap) n = qcap;
    const int2* q = queues + (size_t)combo * qcap;
    for (int i = chunk * 256 + threadIdx.x; i < n; i += FBC2 * 256) {
        long long raw = nt_load_ll(&q[i]);          // read-once stream
        int key = (int)(unsigned)raw;
        int dst = ((unsigned)key) >> 16;
        int src = key & 0xffff;
        int pos = atomicAdd(&cnt[dst], 1);
        if (pos < SLOTS) {
            int2 w; w.x = src; w.y = (int)(raw >> 32);
            ell[(size_t)dst * SLOTS + pos] = w;     // NORMAL store: L2-resident region
        }
    }
}

// ------------- tier-1 direct fill (scalar r9-style, for N>=65536) -----------
__global__ __launch_bounds__(256) void fill_direct(
        const int* __restrict__ eA, const float* __restrict__ attA,
        int* __restrict__ cntA, int2* __restrict__ ellA, int NA,
        const int* __restrict__ eB, const float* __restrict__ attB,
        int* __restrict__ cntB, int2* __restrict__ ellB, int NB, int E) {
    int b = blockIdx.x;
    int combo = b & 15;
    int dir   = combo >> 3;
    int range = combo & 7;
    int chunk = b >> 4;
    const int* e; const float* att; int* cnt; int2* ell; int N;
    if (dir == 0) { e = eA; att = attA; cnt = cntA; ell = ellA; N = NA; }
    else          { e = eB; att = attB; cnt = cntB; ell = ellB; N = NB; }
    int lo = (int)((long)range * N >> 3), hi = (int)((long)(range + 1) * N >> 3);
    for (int i = chunk * 256 + threadIdx.x; i < E; i += HCF * 256) {
        int dst = __builtin_nontemporal_load(&e[E + i]);
        if (dst >= lo && dst < hi) {
            int pos = atomicAdd(&cnt[dst], 1);
            if (pos < SLOTS) {
                int2 v;
                v.x = __builtin_nontemporal_load(&e[i]);
                v.y = __float_as_int(__builtin_nontemporal_load(&att[i]));
                ell[(size_t)dst * SLOTS + pos] = v;
            }
        }
    }
}

// ------- ELL aggregate: XCD-split directions + pk-fma masked pipeline -------
// nt stores for inter-hop bf16 tables (consumed cross-XCD next hop -> push
// toward L3 instead of dirtying writer's L2). Gather loads stay NORMAL.
template <int LAST>
__global__ __launch_bounds__(256) void aggregate6(
        const int* __restrict__ cntA, const int2* __restrict__ ellA,
        const unsigned short* __restrict__ gtA, const unsigned short* __restrict__ fxA,
        unsigned short* __restrict__ obfA, float* __restrict__ of32A, int NA,
        const int* __restrict__ cntB, const int2* __restrict__ ellB,
        const unsigned short* __restrict__ gtB, const unsigned short* __restrict__ fxB,
        unsigned short* __restrict__ obfB, float* __restrict__ of32B, int NB,
        const float* __restrict__ alpha_p) {
    int grp = blockIdx.x >> 3;
    int sub = blockIdx.x & 7;            // XCD id under round-robin
    int rb  = grp * 4 + (sub & 3);       // per-direction row-block index
    int wid = threadIdx.x >> 6;          // wave in block: 0..3
    int lane = threadIdx.x & 63;
    int g = lane >> 4;                   // slot group 0..3
    int l = lane & 15;                   // 16 lanes per edge, 8 elems each
    const int* cnt; const int2* ellbase; const unsigned short* gt; const unsigned short* fx;
    unsigned short* obf; float* of32; int N;
    if (sub < 4) {
        cnt = cntA; ellbase = ellA; gt = gtA; fx = fxA;
        obf = obfA; of32 = of32A; N = NA;
    } else {
        cnt = cntB; ellbase = ellB; gt = gtB; fx = fxB;
        obf = obfB; of32 = of32B; N = NB;
    }
    int row = rb * 4 + wid;
    if (row >= N) return;                // uniform per wave
    int c = cnt[row];
    int deg = c < SLOTS ? c : SLOTS;
    const int2* ent = ellbase + (size_t)row * SLOTS;
    v2f acc2[4];
    acc2[0] = (v2f){0.f, 0.f}; acc2[1] = (v2f){0.f, 0.f};
    acc2[2] = (v2f){0.f, 0.f}; acc2[3] = (v2f){0.f, 0.f};
    int off = l * 8;

#define PROC16(BASE)                                                          \
    {                                                                         \
        unsigned sv[4]; float av[4]; uint4 u[4];                              \
        _Pragma("unroll")                                                     \
        for (int k = 0; k < 4; ++k) {                                         \
            int slot = (BASE) + k * 4 + g;                                    \
            long long rr = nt_load_ll(&ent[slot]);                            \
            bool valid = slot < deg;                                          \
            sv[k] = valid ? (unsigned)rr : 0u;                                \
            av[k] = valid ? __int_as_float((int)(rr >> 32)) : 0.0f;           \
        }                                                                     \
        _Pragma("unroll")                                                     \
        for (int k = 0; k < 4; ++k)                                           \
            u[k] = *reinterpret_cast<const uint4*>(gt + (size_t)sv[k] * D + off); \
        _Pragma("unroll")                                                     \
        for (int k = 0; k < 4; ++k) fma8v(u[k], av[k], acc2);                 \
    }

    PROC16(0);                               // covers deg <= 16 (~84% of rows)
    for (int base = 16; base < deg; base += 16) PROC16(base);
#undef PROC16

    // reduce across the 4 slot-groups (lanes with same l)
    float acc[8];
    #pragma unroll
    for (int k = 0; k < 4; ++k) { acc[2*k] = acc2[k][0]; acc[2*k+1] = acc2[k][1]; }
    #pragma unroll
    for (int k = 0; k < 8; ++k) {
        acc[k] += __shfl_xor(acc[k], 16);
        acc[k] += __shfl_xor(acc[k], 32);
    }
    if (g == 0) {
        float al = alpha_p[0], bl = 1.f - al;
        float fv[8];
        uint4 f = *reinterpret_cast<const uint4*>(fx + (size_t)row * D + off);
        unpack8(f, fv);
        float r[8];
        #pragma unroll
        for (int k = 0; k < 8; ++k)
            r[k] = fminf(fmaxf(fv[k] * al + acc[k] * bl, EPSV), CLIP_HI);
        if (LAST) {
            nt_store4f(of32 + (size_t)row * D + off,     r[0], r[1], r[2], r[3]);
            nt_store4f(of32 + (size_t)row * D + off + 4, r[4], r[5], r[6], r[7]);
        } else {
            uint4 o;
            o.x = (unsigned)f2bf(r[0]) | ((unsigned)f2bf(r[1]) << 16);
            o.y = (unsigned)f2bf(r[2]) | ((unsigned)f2bf(r[3]) << 16);
            o.z = (unsigned)f2bf(r[4]) | ((unsigned)f2bf(r[5]) << 16);
            o.w = (unsigned)f2bf(r[6]) | ((unsigned)f2bf(r[7]) << 16);
            nt_store4u(obf + (size_t)row * D + off, o);   // cross-XCD consumer
        }
    }
}

// ---------------- fallback (atomic scatter) kernels --------------------------
__global__ void scatter_add(const float* __restrict__ cur, const float* __restrict__ att,
                            const int* __restrict__ edges, int E,
                            float* __restrict__ msg) {
    const long long total = (long long)E * (D / 4);
    long long stride = (long long)gridDim.x * blockDim.x;
    for (long long idx = (long long)blockIdx.x * blockDim.x + threadIdx.x;
         idx < total; idx += stride) {
        int e  = (int)(idx >> 5);
        int ch = (int)(idx & 31);
        int src = edges[e];
        int dst = edges[E + e];
        float a = att[e];
        const float4 v = *reinterpret_cast<const float4*>(cur + (size_t)src * D + ch * 4);
        float* p = msg + (size_t)dst * D + ch * 4;
        atomicAdd(p + 0, v.x * a);
        atomicAdd(p + 1, v.y * a);
        atomicAdd(p + 2, v.z * a);
        atomicAdd(p + 3, v.w * a);
    }
}

__global__ void combine(const float4* __restrict__ feat0, const float4* __restrict__ msg,
                        const float* __restrict__ alpha_p, float4* __restrict__ out, int n4) {
    float a = alpha_p[0];
    float b = 1.f - a;
    int stride = gridDim.x * blockDim.x;
    for (int i = blockIdx.x * blockDim.x + threadIdx.x; i < n4; i += stride) {
        float4 f = feat0[i];
        float4 m = msg[i];
        float4 r;
        r.x = fminf(fmaxf(f.x * a + m.x * b, EPSV), CLIP_HI);
        r.y = fminf(fmaxf(f.y * a + m.y * b, EPSV), CLIP_HI);
        r.z = fminf(fmaxf(f.z * a + m.z * b, EPSV), CLIP_HI);
        r.w = fminf(fmaxf(f.w * a + m.w * b, EPSV), CLIP_HI);
        out[i] = r;
    }
}

extern "C" void kernel_launch(void* const* d_in, const int* in_sizes, int n_in,
                              void* d_out, int out_size, void* d_ws, size_t ws_size,
                              hipStream_t stream) {
    const float* xA    = (const float*)d_in[0];
    const float* xB    = (const float*)d_in[1];
    const float* attAB = (const float*)d_in[2];
    const float* attBA = (const float*)d_in[3];
    const float* fc1_w = (const float*)d_in[4];
    const float* fc1_b = (const float*)d_in[5];
    const float* fc2_w = (const float*)d_in[6];
    const float* fc2_b = (const float*)d_in[7];
    const int*   eAB   = (const int*)d_in[8];   // src in A, dst in B
    const int*   eBA   = (const int*)d_in[9];   // src in B, dst in A

    const int NA = in_sizes[0] / D;
    const int NB = in_sizes[1] / D;
    const int E  = in_sizes[2];

    float* out  = (float*)d_out;
    float* outA = out;                      // [NA, D]
    float* outB = out + (size_t)NA * D;     // [NB, D]

    const size_t TBL = (size_t)(NA + NB) * D;   // elements (bf16)

    // ======== tier 0/1: ELL layout ========
    {
        unsigned short* tblP = (unsigned short*)d_ws;
        unsigned short* tblQ = tblP + TBL;
        unsigned short* xtab = tblQ + TBL;
        int2*  ellA  = (int2*)(xtab + TBL);
        int2*  ellB  = ellA + ((size_t)NA * SLOTS + 16);   // +16 pad for masked OOB reads
        int*   cntA  = (int*)(ellB + ((size_t)NB * SLOTS + 16));
        int*   cntB  = cntA + NA;
        int*   qcnt  = cntB + NB;                          // NCOMBO ints
        float* partA = (float*)(qcnt + NCOMBO);
        float* partB = partA + (size_t)G * D;
        float* alpha = partB + (size_t)G * D;
        size_t needed = (size_t)((char*)(alpha + 4) - (char*)d_ws);

        if (ws_size >= needed) {
            unsigned short* xtabA = xtab, *xtabB = xtab + (size_t)NA * D;
            unsigned short* tblPA = tblP, *tblPB = tblP + (size_t)NA * D;
            unsigned short* tblQA = tblQ, *tblQB = tblQ + (size_t)NA * D;

            colsum_bf16<<<G, 256, 0, stream>>>(xA, xB, NA, NB, partA, partB, xtabA, xtabB);
            compute_alpha<<<1, 1024, 0, stream>>>(partA, partB, NA, NB,
                                                  fc1_w, fc1_b, fc2_w, fc2_b, alpha);

            // zero cntA, cntB, qcnt in one memset (contiguous)
            hipMemsetAsync(cntA, 0, ((size_t)NA + NB + NCOMBO) * sizeof(int), stream);

            // queue storage lives in d_out (dead until hop 2)
            int qcap = E / RANGES + E / (4 * RANGES) + 2048;
            bool small_idx = (NA < 65536) && (NB < 65536);
            bool qfit = (size_t)NCOMBO * (size_t)qcap * sizeof(int2)
                        <= (size_t)out_size * sizeof(float);
            if (small_idx && qfit) {
                int2* queues = (int2*)d_out;
                int nbl = (E + EPB - 1) / EPB;
                partition_edges<<<2 * nbl, 256, 0, stream>>>(
                    eBA, attBA, NA, eAB, attAB, NB, E, queues, qcnt, qcap);
                fill_from_queues<<<NCOMBO * FBC2, 256, 0, stream>>>(
                    queues, qcnt, qcap, cntA, ellA, cntB, ellB);
            } else {
                fill_direct<<<16 * HCF, 256, 0, stream>>>(
                    eBA, attBA, cntA, ellA, NA, eAB, attAB, cntB, ellB, NB, E);
            }

            // XCD-split grid: groups of 8 blocks = 4 A-side + 4 B-side
            int gA = (NA + 3) / 4, gB = (NB + 3) / 4;
            int gmax = gA > gB ? gA : gB;
            int grid = ((gmax + 3) / 4) * 8;
            // hop 0: xtab -> tblP
            aggregate6<0><<<grid, 256, 0, stream>>>(
                cntA, ellA, xtabB, xtabA, tblPA, nullptr, NA,
                cntB, ellB, xtabA, xtabB, tblPB, nullptr, NB, alpha);
            // hop 1: tblP -> tblQ
            aggregate6<0><<<grid, 256, 0, stream>>>(
                cntA, ellA, tblPB, xtabA, tblQA, nullptr, NA,
                cntB, ellB, tblPA, xtabB, tblQB, nullptr, NB, alpha);
            // hop 2: tblQ -> d_out (fp32; queues dead by now)
            aggregate6<1><<<grid, 256, 0, stream>>>(
                cntA, ellA, tblQB, xtabA, nullptr, outA, NA,
                cntB, ellB, tblQA, xtabB, nullptr, outB, NB, alpha);
            return;
        }
    }

    // ======== fallback: atomic scatter ========
    {
        float* msgA  = (float*)d_ws;
        float* msgB  = msgA + (size_t)NA * D;
        float* pA    = msgB + (size_t)NB * D;
        float* pB    = pA + (size_t)G * D;
        float* alph  = pB + (size_t)G * D;

        colsum_bf16<<<G, 256, 0, stream>>>(xA, xB, NA, NB, pA, pB,
                                           (unsigned short*)msgA, (unsigned short*)msgB);
        compute_alpha<<<1, 1024, 0, stream>>>(pA, pB, NA, NB,
                                              fc1_w, fc1_b, fc2_w, fc2_b, alph);

        const size_t msgBytes = ((size_t)NA + (size_t)NB) * D * sizeof(float);
        for (int hop = 0; hop < 3; ++hop) {
            hipMemsetAsync(msgA, 0, msgBytes, stream);
            const float* fA = (hop == 0) ? xA : outA;
            const float* fB = (hop == 0) ? xB : outB;
            scatter_add<<<4096, 256, 0, stream>>>(fB, attBA, eBA, E, msgA);
            scatter_add<<<4096, 256, 0, stream>>>(fA, attAB, eAB, E, msgB);
            combine<<<2048, 256, 0, stream>>>((const float4*)xA, (const float4*)msgA,
                                              alph, (float4*)outA, NA * D / 4);
            combine<<<2048, 256, 0, stream>>>((const float4*)xB, (const float4*)msgB,
                                              alph, (float4*)outB, NB * D / 4);
        }
    }
}